// Round 14
// baseline (306.898 us; speedup 1.0000x reference)
//
#include <hip/hip_runtime.h>
#include <math.h>

#define NROWS 16384
#define DIN   2048
#define H1D   256
#define H2D   128
#define NE    64
#define EPS_MARGIN 2e-4f
#define SQRT1_2 0.70710678118654752440084436210485
#define IBIG 0x7fffffff

typedef short  bf16x8 __attribute__((ext_vector_type(8)));
typedef float  f32x4  __attribute__((ext_vector_type(4)));
typedef __attribute__((address_space(3))) void lds_void;
typedef __attribute__((address_space(1))) const void glob_void;

#define GLDS16(src, dst) \
    __builtin_amdgcn_global_load_lds((glob_void*)(src), (lds_void*)(dst), 16, 0, 0)

// ---------------- workspace layout ----------------
#define WS_OFF_ROWS 64
#define WS_OFF_W1FH 66560
#define WS_OFF_W1FL (WS_OFF_W1FH + DIN*H1D*2)          // 2163712
#define WS_OFF_H1G  (WS_OFF_W1FL + DIN*H1D*2)          // 4260864
#define WS_NEED_FUSED (size_t)WS_OFF_H1G
#define WS_NEED_SPLIT (size_t)(WS_OFF_H1G + (size_t)NROWS*H1D*4)   // ~20.1 MB

__device__ __forceinline__ void split_bf16(float v, unsigned short& h, unsigned short& l) {
    unsigned int u = __float_as_uint(v);
    unsigned int rh = u + 0x7FFFu + ((u >> 16) & 1u);
    h = (unsigned short)(rh >> 16);
    float hf = __uint_as_float((unsigned int)h << 16);
    float r = v - hf;
    unsigned int u2 = __float_as_uint(r);
    unsigned int rl = u2 + 0x7FFFu + ((u2 >> 16) & 1u);
    l = (unsigned short)(rl >> 16);
}

__device__ __forceinline__ void split_fast(float v, short& h, short& l) {
    unsigned int u = __float_as_uint(v);
    unsigned int rh = (u + 0x7FFFu + ((u >> 16) & 1u)) >> 16;
    h = (short)rh;
    float r = v - __uint_as_float(rh << 16);
    l = (short)(__float_as_uint(r) >> 16);
}

__device__ __forceinline__ bool gtr(float a, int ia, float b, int ib) {
    return a > b || (a == b && ia < ib);
}
__device__ __forceinline__ void ins3(float v, int iv,
                                     float& t1, int& j1, float& t2, int& j2, float& t3, int& j3) {
    if (gtr(v, iv, t1, j1))      { t3 = t2; j3 = j2; t2 = t1; j2 = j1; t1 = v; j1 = iv; }
    else if (gtr(v, iv, t2, j2)) { t3 = t2; j3 = j2; t2 = v;  j2 = iv; }
    else if (gtr(v, iv, t3, j3)) { t3 = v;  j3 = iv; }
}

// ---------------- prep: w1 -> fragment-ordered split-bf16 (+ ws_count init) ----------------
__global__ void prep_w1f_kernel(const float* __restrict__ w1,
                                unsigned short* __restrict__ w1f_hi,
                                unsigned short* __restrict__ w1f_lo,
                                unsigned int* __restrict__ ws_count)
{
    if (blockIdx.x == 0 && threadIdx.x == 0) *ws_count = 0u;
    const int g    = blockIdx.x * 256 + threadIdx.x;
    const int st   = g >> 10;
    const int cb   = (g >> 6) & 15;
    const int lane = g & 63;
    const int col  = cb * 16 + (lane & 15);
    const int k0   = st * 32 + (lane >> 4) * 8;
    unsigned short vh[8], vl[8];
    #pragma unroll
    for (int j = 0; j < 8; ++j) {
        float v = w1[(size_t)(k0 + j) * H1D + col];
        split_bf16(v, vh[j], vl[j]);
    }
    *(uint4*)(w1f_hi + (size_t)g * 8) = *(uint4*)vh;
    *(uint4*)(w1f_lo + (size_t)g * 8) = *(uint4*)vl;
}

// ---------------- GEMM tile geometry (R13, proven) ----------------
#define BM 32
#define KSTEPS (DIN / 32)     // 64
#define OFF_AB  0
#define OFF_BH  8192
#define OFF_BL  40960
#define OFF_H1  0
#define H1P     264
#define OFF_H2  33792
#define H2P     132
#define OFF_RED 50688
#define SMEM_SZ 73728

// ===================== split pass 1: GEMM1 + LN + GELU -> h1g =====================
__global__ __launch_bounds__(512, 4)
void gemm1_ln_kernel(const float* __restrict__ x,
                     const float* __restrict__ b1, const float* __restrict__ g1,
                     const float* __restrict__ be1,
                     const unsigned short* __restrict__ w1f_hi,
                     const unsigned short* __restrict__ w1f_lo,
                     float* __restrict__ h1g)
{
    __shared__ __align__(16) char smem[SMEM_SZ];
    float*  sH1  = (float*)(smem + OFF_H1);
    float2* sRed = (float2*)(smem + OFF_RED);

    const int tid  = threadIdx.x;
    const int lane = tid & 63;
    const int wid  = tid >> 6;
    const int wr   = wid >> 2;
    const int wc   = wid & 3;
    const int lr   = lane & 15;
    const int lg   = lane >> 4;
    const int r0   = blockIdx.x * BM;

    const int arow = (wid & 3) * 8 + (lane >> 3);
    const int aseg = lane & 7;
    const float* asrc = x + (size_t)(r0 + arow) * DIN + ((aseg ^ (arow & 7)) << 2);
    const unsigned short* bsh0 = w1f_hi + ((size_t)((wid * 2 + 0) * 64 + lane)) * 8;
    const unsigned short* bsh1 = w1f_hi + ((size_t)((wid * 2 + 1) * 64 + lane)) * 8;
    const unsigned short* bsl0 = w1f_lo + ((size_t)((wid * 2 + 0) * 64 + lane)) * 8;
    const unsigned short* bsl1 = w1f_lo + ((size_t)((wid * 2 + 1) * 64 + lane)) * 8;

#define STAGE(buf_, st_) do { \
    if (wid < 4) GLDS16(asrc + (size_t)(st_) * 32, smem + OFF_AB + (buf_) * 4096 + wid * 1024); \
    GLDS16(bsh0 + (size_t)(st_) * 8192, smem + OFF_BH + (buf_) * 16384 + (wid * 2 + 0) * 1024); \
    GLDS16(bsh1 + (size_t)(st_) * 8192, smem + OFF_BH + (buf_) * 16384 + (wid * 2 + 1) * 1024); \
    GLDS16(bsl0 + (size_t)(st_) * 8192, smem + OFF_BL + (buf_) * 16384 + (wid * 2 + 0) * 1024); \
    GLDS16(bsl1 + (size_t)(st_) * 8192, smem + OFF_BL + (buf_) * 16384 + (wid * 2 + 1) * 1024); \
} while (0)

    f32x4 acc[4];
    #pragma unroll
    for (int t = 0; t < 4; ++t) acc[t] = (f32x4){0.f, 0.f, 0.f, 0.f};

    STAGE(0, 0);
    __syncthreads();
    int cur = 0;
    for (int st = 0; st < KSTEPS; ++st) {
        if (st + 1 < KSTEPS) STAGE(cur ^ 1, st + 1);
        bf16x8 ah, al;
        {
            int row = wr * 16 + lr;
            int g0  = (2 * lg) ^ (lr & 7);
            const char* abase = smem + OFF_AB + cur * 4096 + row * 128;
            float4 q0 = *(const float4*)(abase + g0 * 16);
            float4 q1 = *(const float4*)(abase + (g0 ^ 1) * 16);
            float af[8] = {q0.x, q0.y, q0.z, q0.w, q1.x, q1.y, q1.z, q1.w};
            #pragma unroll
            for (int j = 0; j < 8; ++j) {
                short h, l;
                split_fast(af[j], h, l);
                ah[j] = h; al[j] = l;
            }
        }
        bf16x8 bh[4], bl[4];
        #pragma unroll
        for (int t = 0; t < 4; ++t) {
            int cb = wc * 4 + t;
            bh[t] = *(const bf16x8*)(smem + OFF_BH + cur * 16384 + cb * 1024 + lane * 16);
            bl[t] = *(const bf16x8*)(smem + OFF_BL + cur * 16384 + cb * 1024 + lane * 16);
        }
        #pragma unroll
        for (int t = 0; t < 4; ++t) {
            acc[t] = __builtin_amdgcn_mfma_f32_16x16x32_bf16(ah, bh[t], acc[t], 0, 0, 0);
            acc[t] = __builtin_amdgcn_mfma_f32_16x16x32_bf16(ah, bl[t], acc[t], 0, 0, 0);
            acc[t] = __builtin_amdgcn_mfma_f32_16x16x32_bf16(al, bh[t], acc[t], 0, 0, 0);
        }
        __syncthreads();
        cur ^= 1;
    }
#undef STAGE

    // bias + LN(256) + GELU -> sH1
    float tb[4], tg[4], tbe[4];
    #pragma unroll
    for (int t = 0; t < 4; ++t) {
        int col = wc * 64 + t * 16 + lr;
        tb[t] = b1[col]; tg[t] = g1[col]; tbe[t] = be1[col];
    }
    #pragma unroll
    for (int t = 0; t < 4; ++t)
        #pragma unroll
        for (int rg = 0; rg < 4; ++rg)
            acc[t][rg] += tb[t];

    #pragma unroll
    for (int rg = 0; rg < 4; ++rg) {
        float p1 = 0.f, p2 = 0.f;
        #pragma unroll
        for (int t = 0; t < 4; ++t) { float v = acc[t][rg]; p1 += v; p2 += v * v; }
        p1 += __shfl_xor(p1, 1, 64); p2 += __shfl_xor(p2, 1, 64);
        p1 += __shfl_xor(p1, 2, 64); p2 += __shfl_xor(p2, 2, 64);
        p1 += __shfl_xor(p1, 4, 64); p2 += __shfl_xor(p2, 4, 64);
        p1 += __shfl_xor(p1, 8, 64); p2 += __shfl_xor(p2, 8, 64);
        if (lr == 0) {
            int row = wr * 16 + lg * 4 + rg;
            sRed[row * 4 + wc] = make_float2(p1, p2);
        }
    }
    __syncthreads();

    #pragma unroll
    for (int rg = 0; rg < 4; ++rg) {
        int row = wr * 16 + lg * 4 + rg;
        float2 q0 = sRed[row * 4 + 0], q1 = sRed[row * 4 + 1];
        float2 q2 = sRed[row * 4 + 2], q3 = sRed[row * 4 + 3];
        float s1 = (q0.x + q1.x) + (q2.x + q3.x);
        float s2 = (q0.y + q1.y) + (q2.y + q3.y);
        float mu  = s1 * (1.0f / H1D);
        float var = s2 * (1.0f / H1D) - mu * mu;
        float rs  = rsqrtf(var + 1e-5f);
        #pragma unroll
        for (int t = 0; t < 4; ++t) {
            int col = wc * 64 + t * 16 + lr;
            float v = (acc[t][rg] - mu) * rs * tg[t] + tbe[t];
            v = 0.5f * v * (1.0f + erff(v * (float)SQRT1_2));
            sH1[row * H1P + col] = v;
        }
    }
    __syncthreads();

    // write h1 tile to global (coalesced float4)
    #pragma unroll
    for (int i = 0; i < 4; ++i) {
        int u = tid + i * 512;       // 0..2047
        int row = u >> 6, f4 = u & 63;
        float4 v = *(const float4*)&sH1[row * H1P + f4 * 4];
        *(float4*)(h1g + (size_t)(r0 + row) * H1D + f4 * 4) = v;
    }
}

// ===================== split pass 2: stage2 + stage3 + top-3 =====================
__global__ __launch_bounds__(256, 4)
void tail_kernel(const float* __restrict__ h1g,
                 const float* __restrict__ w2, const float* __restrict__ b2,
                 const float* __restrict__ g2, const float* __restrict__ be2,
                 const float* __restrict__ w3, const float* __restrict__ b3,
                 const float* __restrict__ temperature,
                 float* __restrict__ out_gates,
                 float* __restrict__ out_idx,
                 float* __restrict__ out_logits,
                 unsigned int* __restrict__ ws_count,
                 int* __restrict__ ws_rows)
{
    __shared__ __align__(16) float sH1[32 * H1P];
    __shared__ __align__(16) float sH2[32 * H2P];

    const int tid = threadIdx.x;
    const int r0  = blockIdx.x * 32;

    // load h1 tile 32x256 (coalesced)
    #pragma unroll
    for (int i = 0; i < 8; ++i) {
        int u = tid + i * 256;       // 0..2047
        int row = u >> 6, f4 = u & 63;
        *(float4*)&sH1[row * H1P + f4 * 4] =
            *(const float4*)(h1g + (size_t)(r0 + row) * H1D + f4 * 4);
    }
    __syncthreads();

    // ---------- Stage 2 (round-6 proven): 32x128, 256 threads ----------
    const int tx = tid & 31;
    const int ty = tid >> 5;
    float acc2[4][4];
    #pragma unroll
    for (int i = 0; i < 4; ++i)
        #pragma unroll
        for (int j = 0; j < 4; ++j) acc2[i][j] = 0.f;
    {
        const float* w2p = w2 + tx * 4;
        #pragma unroll 2
        for (int k = 0; k < H1D; ++k) {
            float4 wv4 = *(const float4*)(w2p + (size_t)k * H2D);
            float wr4[4] = {wv4.x, wv4.y, wv4.z, wv4.w};
            float ar4[4];
            #pragma unroll
            for (int i = 0; i < 4; ++i) ar4[i] = sH1[(ty * 4 + i) * H1P + k];
            #pragma unroll
            for (int i = 0; i < 4; ++i)
                #pragma unroll
                for (int j = 0; j < 4; ++j)
                    acc2[i][j] = fmaf(ar4[i], wr4[j], acc2[i][j]);
        }
    }
    {
        float b2v[4], g2v[4], be2v[4];
        #pragma unroll
        for (int j = 0; j < 4; ++j) {
            b2v[j] = b2[tx * 4 + j]; g2v[j] = g2[tx * 4 + j]; be2v[j] = be2[tx * 4 + j];
        }
        #pragma unroll
        for (int i = 0; i < 4; ++i) {
            float s1 = 0.f, s2 = 0.f, vv[4];
            #pragma unroll
            for (int j = 0; j < 4; ++j) {
                float v = acc2[i][j] + b2v[j];
                vv[j] = v; s1 += v; s2 += v * v;
            }
            s1 += __shfl_xor(s1, 1, 64);  s2 += __shfl_xor(s2, 1, 64);
            s1 += __shfl_xor(s1, 2, 64);  s2 += __shfl_xor(s2, 2, 64);
            s1 += __shfl_xor(s1, 4, 64);  s2 += __shfl_xor(s2, 4, 64);
            s1 += __shfl_xor(s1, 8, 64);  s2 += __shfl_xor(s2, 8, 64);
            s1 += __shfl_xor(s1, 16, 64); s2 += __shfl_xor(s2, 16, 64);
            float mu  = s1 * (1.0f / H2D);
            float var = s2 * (1.0f / H2D) - mu * mu;
            float rs  = rsqrtf(var + 1e-5f);
            #pragma unroll
            for (int j = 0; j < 4; ++j) {
                float v = (vv[j] - mu) * rs * g2v[j] + be2v[j];
                v = 0.5f * v * (1.0f + erff(v * (float)SQRT1_2));
                sH2[(ty * 4 + i) * H2P + tx * 4 + j] = v;
            }
        }
    }
    __syncthreads();

    // ---------- Stage 3 + top-3 (round-6 proven): q=tid&7, r=tid>>3 ----------
    const int q = tid & 7;
    const int r = tid >> 3;
    float acc3[8];
    #pragma unroll
    for (int j = 0; j < 8; ++j) acc3[j] = 0.f;
    {
        const float* w3p = w3 + q * 8;
        #pragma unroll 4
        for (int k = 0; k < H2D; ++k) {
            float hv = sH2[r * H2P + k];
            float4 wa = *(const float4*)(w3p + (size_t)k * NE);
            float4 wb = *(const float4*)(w3p + (size_t)k * NE + 4);
            acc3[0] = fmaf(hv, wa.x, acc3[0]);
            acc3[1] = fmaf(hv, wa.y, acc3[1]);
            acc3[2] = fmaf(hv, wa.z, acc3[2]);
            acc3[3] = fmaf(hv, wa.w, acc3[3]);
            acc3[4] = fmaf(hv, wb.x, acc3[4]);
            acc3[5] = fmaf(hv, wb.y, acc3[5]);
            acc3[6] = fmaf(hv, wb.z, acc3[6]);
            acc3[7] = fmaf(hv, wb.w, acc3[7]);
        }
    }
    float tinv = 1.0f / fmaxf(temperature[0], 0.1f);
    float lg8[8];
    #pragma unroll
    for (int j = 0; j < 8; ++j) lg8[j] = (acc3[j] + b3[q * 8 + j]) * tinv;

    *(float4*)(out_logits + (size_t)(r0 + r) * NE + q * 8)     = make_float4(lg8[0], lg8[1], lg8[2], lg8[3]);
    *(float4*)(out_logits + (size_t)(r0 + r) * NE + q * 8 + 4) = make_float4(lg8[4], lg8[5], lg8[6], lg8[7]);

    float v1 = -INFINITY, v2 = -INFINITY, v3 = -INFINITY;
    int   i1 = IBIG, i2 = IBIG, i3 = IBIG;
    #pragma unroll
    for (int j = 0; j < 8; ++j) ins3(lg8[j], q * 8 + j, v1, i1, v2, i2, v3, i3);
    #pragma unroll
    for (int m = 1; m < 8; m <<= 1) {
        float c1v = __shfl_xor(v1, m, 64); int cj1 = __shfl_xor(i1, m, 64);
        float c2v = __shfl_xor(v2, m, 64); int cj2 = __shfl_xor(i2, m, 64);
        float c3v = __shfl_xor(v3, m, 64); int cj3 = __shfl_xor(i3, m, 64);
        ins3(c1v, cj1, v1, i1, v2, i2, v3, i3);
        ins3(c2v, cj2, v1, i1, v2, i2, v3, i3);
        ins3(c3v, cj3, v1, i1, v2, i2, v3, i3);
    }

    float e2  = expf(v2 - v1);
    float den = 1.0f + e2;
    float tg1 = 1.0f / den;
    float tg2 = e2 / den;
    float ssum = tg1 + tg2 + 1e-8f;
    float gv1 = tg1 / ssum;
    float gv2 = tg2 / ssum;

    if (q == 0) {
        float margin = fminf(v1 - v2, v2 - v3);
        if (!(margin >= EPS_MARGIN)) {
            unsigned int slot = atomicAdd(ws_count, 1u);
            if ((int)slot < NROWS) ws_rows[slot] = r0 + r;
        }
        out_idx[(size_t)(r0 + r) * 2 + 0] = (float)i1;
        out_idx[(size_t)(r0 + r) * 2 + 1] = (float)i2;
    }
    {
        float gvv[8];
        #pragma unroll
        for (int j = 0; j < 8; ++j) {
            int c = q * 8 + j;
            gvv[j] = (c == i1) ? gv1 : ((c == i2) ? gv2 : 0.0f);
        }
        *(float4*)(out_gates + (size_t)(r0 + r) * NE + q * 8)     = make_float4(gvv[0], gvv[1], gvv[2], gvv[3]);
        *(float4*)(out_gates + (size_t)(r0 + r) * NE + q * 8 + 4) = make_float4(gvv[4], gvv[5], gvv[6], gvv[7]);
    }
}

// ===================== fused fallback (R13 verbatim, passing) =====================
__global__ __launch_bounds__(512, 4)
void gate_fused_kernel(const float* __restrict__ x,
                       const float* __restrict__ b1, const float* __restrict__ g1,
                       const float* __restrict__ be1,
                       const float* __restrict__ w2, const float* __restrict__ b2,
                       const float* __restrict__ g2, const float* __restrict__ be2,
                       const float* __restrict__ w3, const float* __restrict__ b3,
                       const float* __restrict__ temperature,
                       const unsigned short* __restrict__ w1f_hi,
                       const unsigned short* __restrict__ w1f_lo,
                       float* __restrict__ out_gates,
                       float* __restrict__ out_idx,
                       float* __restrict__ out_logits,
                       unsigned int* __restrict__ ws_count,
                       int* __restrict__ ws_rows)
{
    __shared__ __align__(16) char smem[SMEM_SZ];
    float*  sH1  = (float*)(smem + OFF_H1);
    float*  sH2  = (float*)(smem + OFF_H2);
    float2* sRed = (float2*)(smem + OFF_RED);

    const int tid  = threadIdx.x;
    const int lane = tid & 63;
    const int wid  = tid >> 6;
    const int wr   = wid >> 2;
    const int wc   = wid & 3;
    const int lr   = lane & 15;
    const int lg   = lane >> 4;
    const int r0   = blockIdx.x * BM;

    const int arow = (wid & 3) * 8 + (lane >> 3);
    const int aseg = lane & 7;
    const float* asrc = x + (size_t)(r0 + arow) * DIN + ((aseg ^ (arow & 7)) << 2);
    const unsigned short* bsh0 = w1f_hi + ((size_t)((wid * 2 + 0) * 64 + lane)) * 8;
    const unsigned short* bsh1 = w1f_hi + ((size_t)((wid * 2 + 1) * 64 + lane)) * 8;
    const unsigned short* bsl0 = w1f_lo + ((size_t)((wid * 2 + 0) * 64 + lane)) * 8;
    const unsigned short* bsl1 = w1f_lo + ((size_t)((wid * 2 + 1) * 64 + lane)) * 8;

#define STAGE(buf_, st_) do { \
    if (wid < 4) GLDS16(asrc + (size_t)(st_) * 32, smem + OFF_AB + (buf_) * 4096 + wid * 1024); \
    GLDS16(bsh0 + (size_t)(st_) * 8192, smem + OFF_BH + (buf_) * 16384 + (wid * 2 + 0) * 1024); \
    GLDS16(bsh1 + (size_t)(st_) * 8192, smem + OFF_BH + (buf_) * 16384 + (wid * 2 + 1) * 1024); \
    GLDS16(bsl0 + (size_t)(st_) * 8192, smem + OFF_BL + (buf_) * 16384 + (wid * 2 + 0) * 1024); \
    GLDS16(bsl1 + (size_t)(st_) * 8192, smem + OFF_BL + (buf_) * 16384 + (wid * 2 + 1) * 1024); \
} while (0)

    f32x4 acc[4];
    #pragma unroll
    for (int t = 0; t < 4; ++t) acc[t] = (f32x4){0.f, 0.f, 0.f, 0.f};

    STAGE(0, 0);
    __syncthreads();
    int cur = 0;
    for (int st = 0; st < KSTEPS; ++st) {
        if (st + 1 < KSTEPS) STAGE(cur ^ 1, st + 1);
        bf16x8 ah, al;
        {
            int row = wr * 16 + lr;
            int g0  = (2 * lg) ^ (lr & 7);
            const char* abase = smem + OFF_AB + cur * 4096 + row * 128;
            float4 q0 = *(const float4*)(abase + g0 * 16);
            float4 q1 = *(const float4*)(abase + (g0 ^ 1) * 16);
            float af[8] = {q0.x, q0.y, q0.z, q0.w, q1.x, q1.y, q1.z, q1.w};
            #pragma unroll
            for (int j = 0; j < 8; ++j) {
                short h, l;
                split_fast(af[j], h, l);
                ah[j] = h; al[j] = l;
            }
        }
        bf16x8 bh[4], bl[4];
        #pragma unroll
        for (int t = 0; t < 4; ++t) {
            int cb = wc * 4 + t;
            bh[t] = *(const bf16x8*)(smem + OFF_BH + cur * 16384 + cb * 1024 + lane * 16);
            bl[t] = *(const bf16x8*)(smem + OFF_BL + cur * 16384 + cb * 1024 + lane * 16);
        }
        #pragma unroll
        for (int t = 0; t < 4; ++t) {
            acc[t] = __builtin_amdgcn_mfma_f32_16x16x32_bf16(ah, bh[t], acc[t], 0, 0, 0);
            acc[t] = __builtin_amdgcn_mfma_f32_16x16x32_bf16(ah, bl[t], acc[t], 0, 0, 0);
            acc[t] = __builtin_amdgcn_mfma_f32_16x16x32_bf16(al, bh[t], acc[t], 0, 0, 0);
        }
        __syncthreads();
        cur ^= 1;
    }
#undef STAGE

    float tb[4], tg[4], tbe[4];
    #pragma unroll
    for (int t = 0; t < 4; ++t) {
        int col = wc * 64 + t * 16 + lr;
        tb[t] = b1[col]; tg[t] = g1[col]; tbe[t] = be1[col];
    }
    #pragma unroll
    for (int t = 0; t < 4; ++t)
        #pragma unroll
        for (int rg = 0; rg < 4; ++rg)
            acc[t][rg] += tb[t];

    #pragma unroll
    for (int rg = 0; rg < 4; ++rg) {
        float p1 = 0.f, p2 = 0.f;
        #pragma unroll
        for (int t = 0; t < 4; ++t) { float v = acc[t][rg]; p1 += v; p2 += v * v; }
        p1 += __shfl_xor(p1, 1, 64); p2 += __shfl_xor(p2, 1, 64);
        p1 += __shfl_xor(p1, 2, 64); p2 += __shfl_xor(p2, 2, 64);
        p1 += __shfl_xor(p1, 4, 64); p2 += __shfl_xor(p2, 4, 64);
        p1 += __shfl_xor(p1, 8, 64); p2 += __shfl_xor(p2, 8, 64);
        if (lr == 0) {
            int row = wr * 16 + lg * 4 + rg;
            sRed[row * 4 + wc] = make_float2(p1, p2);
        }
    }
    __syncthreads();

    #pragma unroll
    for (int rg = 0; rg < 4; ++rg) {
        int row = wr * 16 + lg * 4 + rg;
        float2 q0 = sRed[row * 4 + 0], q1 = sRed[row * 4 + 1];
        float2 q2 = sRed[row * 4 + 2], q3 = sRed[row * 4 + 3];
        float s1 = (q0.x + q1.x) + (q2.x + q3.x);
        float s2 = (q0.y + q1.y) + (q2.y + q3.y);
        float mu  = s1 * (1.0f / H1D);
        float var = s2 * (1.0f / H1D) - mu * mu;
        float rs  = rsqrtf(var + 1e-5f);
        #pragma unroll
        for (int t = 0; t < 4; ++t) {
            int col = wc * 64 + t * 16 + lr;
            float v = (acc[t][rg] - mu) * rs * tg[t] + tbe[t];
            v = 0.5f * v * (1.0f + erff(v * (float)SQRT1_2));
            sH1[row * H1P + col] = v;
        }
    }
    __syncthreads();

    const int tx = tid & 31;
    const int ty = tid >> 5;
    float acc2[2][4];
    #pragma unroll
    for (int i = 0; i < 2; ++i)
        #pragma unroll
        for (int j = 0; j < 4; ++j) acc2[i][j] = 0.f;
    {
        const float* w2p = w2 + tx * 4;
        #pragma unroll 4
        for (int k = 0; k < H1D; ++k) {
            float4 wv4 = *(const float4*)(w2p + (size_t)k * H2D);
            float wr4[4] = {wv4.x, wv4.y, wv4.z, wv4.w};
            float ar0 = sH1[(ty * 2 + 0) * H1P + k];
            float ar1 = sH1[(ty * 2 + 1) * H1P + k];
            #pragma unroll
            for (int j = 0; j < 4; ++j) {
                acc2[0][j] = fmaf(ar0, wr4[j], acc2[0][j]);
                acc2[1][j] = fmaf(ar1, wr4[j], acc2[1][j]);
            }
        }
    }
    {
        float b2v[4], g2v[4], be2v[4];
        #pragma unroll
        for (int j = 0; j < 4; ++j) {
            b2v[j] = b2[tx * 4 + j]; g2v[j] = g2[tx * 4 + j]; be2v[j] = be2[tx * 4 + j];
        }
        #pragma unroll
        for (int i = 0; i < 2; ++i) {
            float s1 = 0.f, s2 = 0.f, vv[4];
            #pragma unroll
            for (int j = 0; j < 4; ++j) {
                float v = acc2[i][j] + b2v[j];
                vv[j] = v; s1 += v; s2 += v * v;
            }
            s1 += __shfl_xor(s1, 1, 64);  s2 += __shfl_xor(s2, 1, 64);
            s1 += __shfl_xor(s1, 2, 64);  s2 += __shfl_xor(s2, 2, 64);
            s1 += __shfl_xor(s1, 4, 64);  s2 += __shfl_xor(s2, 4, 64);
            s1 += __shfl_xor(s1, 8, 64);  s2 += __shfl_xor(s2, 8, 64);
            s1 += __shfl_xor(s1, 16, 64); s2 += __shfl_xor(s2, 16, 64);
            float mu  = s1 * (1.0f / H2D);
            float var = s2 * (1.0f / H2D) - mu * mu;
            float rs  = rsqrtf(var + 1e-5f);
            #pragma unroll
            for (int j = 0; j < 4; ++j) {
                float v = (vv[j] - mu) * rs * g2v[j] + be2v[j];
                v = 0.5f * v * (1.0f + erff(v * (float)SQRT1_2));
                sH2[(ty * 2 + i) * H2P + tx * 4 + j] = v;
            }
        }
    }
    __syncthreads();

    const int q = tid & 15;
    const int r = tid >> 4;
    float acc3[4];
    #pragma unroll
    for (int j = 0; j < 4; ++j) acc3[j] = 0.f;
    {
        const float* w3p = w3 + q * 4;
        #pragma unroll 4
        for (int k = 0; k < H2D; ++k) {
            float hv = sH2[r * H2P + k];
            float4 wa = *(const float4*)(w3p + (size_t)k * NE);
            acc3[0] = fmaf(hv, wa.x, acc3[0]);
            acc3[1] = fmaf(hv, wa.y, acc3[1]);
            acc3[2] = fmaf(hv, wa.z, acc3[2]);
            acc3[3] = fmaf(hv, wa.w, acc3[3]);
        }
    }
    float tinv = 1.0f / fmaxf(temperature[0], 0.1f);
    float lg4[4];
    #pragma unroll
    for (int j = 0; j < 4; ++j) lg4[j] = (acc3[j] + b3[q * 4 + j]) * tinv;

    *(float4*)(out_logits + (size_t)(r0 + r) * NE + q * 4) = make_float4(lg4[0], lg4[1], lg4[2], lg4[3]);

    float v1 = -INFINITY, v2 = -INFINITY, v3 = -INFINITY;
    int   i1 = IBIG, i2 = IBIG, i3 = IBIG;
    #pragma unroll
    for (int j = 0; j < 4; ++j) ins3(lg4[j], q * 4 + j, v1, i1, v2, i2, v3, i3);
    #pragma unroll
    for (int m = 1; m < 16; m <<= 1) {
        float c1v = __shfl_xor(v1, m, 64); int cj1 = __shfl_xor(i1, m, 64);
        float c2v = __shfl_xor(v2, m, 64); int cj2 = __shfl_xor(i2, m, 64);
        float c3v = __shfl_xor(v3, m, 64); int cj3 = __shfl_xor(i3, m, 64);
        ins3(c1v, cj1, v1, i1, v2, i2, v3, i3);
        ins3(c2v, cj2, v1, i1, v2, i2, v3, i3);
        ins3(c3v, cj3, v1, i1, v2, i2, v3, i3);
    }

    float e2  = expf(v2 - v1);
    float den = 1.0f + e2;
    float tg1 = 1.0f / den;
    float tg2 = e2 / den;
    float ssum = tg1 + tg2 + 1e-8f;
    float gv1 = tg1 / ssum;
    float gv2 = tg2 / ssum;

    if (q == 0) {
        float margin = fminf(v1 - v2, v2 - v3);
        if (!(margin >= EPS_MARGIN)) {
            unsigned int slot = atomicAdd(ws_count, 1u);
            if ((int)slot < NROWS) ws_rows[slot] = r0 + r;
        }
        out_idx[(size_t)(r0 + r) * 2 + 0] = (float)i1;
        out_idx[(size_t)(r0 + r) * 2 + 1] = (float)i2;
    }
    {
        float gvv[4];
        #pragma unroll
        for (int j = 0; j < 4; ++j) {
            int c = q * 4 + j;
            gvv[j] = (c == i1) ? gv1 : ((c == i2) ? gv2 : 0.0f);
        }
        *(float4*)(out_gates + (size_t)(r0 + r) * NE + q * 4) = make_float4(gvv[0], gvv[1], gvv[2], gvv[3]);
    }
}

// ---------------- pass B: f64 repair, 1024 threads, K-sliced ----------------
__global__ __launch_bounds__(1024, 1)
void repair_f64_kernel(const float* __restrict__ x,
                       const float* __restrict__ w1, const float* __restrict__ b1,
                       const float* __restrict__ g1, const float* __restrict__ be1,
                       const float* __restrict__ w2, const float* __restrict__ b2,
                       const float* __restrict__ g2, const float* __restrict__ be2,
                       const float* __restrict__ w3, const float* __restrict__ b3,
                       const float* __restrict__ temperature,
                       float* __restrict__ out_gates,
                       float* __restrict__ out_idx,
                       const unsigned int* __restrict__ ws_count,
                       const int* __restrict__ ws_rows)
{
    __shared__ float  sxr[DIN];
    __shared__ double sPart[1024];
    __shared__ double sh1[H1D];
    __shared__ double sh2[H2D];
    __shared__ double sred[32];

    const int t = threadIdx.x;
    const int lane = t & 63, w = t >> 6;
    const unsigned int n = *ws_count;
    const double tinv = 1.0 / fmax((double)temperature[0], 0.1);

    for (unsigned int wi = blockIdx.x; wi < n; wi += gridDim.x) {
        const int row = ws_rows[wi];

        const float4* xr4 = (const float4*)(x + (size_t)row * DIN);
        if (t < DIN / 4) ((float4*)sxr)[t] = xr4[t];
        __syncthreads();

        {
            const int c = t & 255, sl = t >> 8;
            const float* w1c = w1 + c;
            const int kb = sl * 512;
            double a0 = 0, a1 = 0, a2 = 0, a3 = 0;
            for (int k = 0; k < 512; k += 4) {
                int kk = kb + k;
                a0 = fma((double)sxr[kk + 0], (double)w1c[(size_t)(kk + 0) * H1D], a0);
                a1 = fma((double)sxr[kk + 1], (double)w1c[(size_t)(kk + 1) * H1D], a1);
                a2 = fma((double)sxr[kk + 2], (double)w1c[(size_t)(kk + 2) * H1D], a2);
                a3 = fma((double)sxr[kk + 3], (double)w1c[(size_t)(kk + 3) * H1D], a3);
            }
            sPart[sl * 256 + c] = (a0 + a1) + (a2 + a3);
        }
        __syncthreads();
        double c1 = 0.0;
        if (t < 256) {
            c1 = ((sPart[0 * 256 + t] + sPart[1 * 256 + t]) +
                  (sPart[2 * 256 + t] + sPart[3 * 256 + t])) + (double)b1[t];
            double s1 = c1, s2 = c1 * c1;
            for (int m = 1; m < 64; m <<= 1) { s1 += __shfl_xor(s1, m, 64); s2 += __shfl_xor(s2, m, 64); }
            if (lane == 0) { sred[w * 2] = s1; sred[w * 2 + 1] = s2; }
        }
        __syncthreads();
        if (t < 256) {
            double s1 = (sred[0] + sred[2]) + (sred[4] + sred[6]);
            double s2 = (sred[1] + sred[3]) + (sred[5] + sred[7]);
            double mu  = s1 * (1.0 / H1D);
            double var = s2 * (1.0 / H1D) - mu * mu;
            double rs  = 1.0 / sqrt(var + 1e-5);
            double vn  = (c1 - mu) * rs * (double)g1[t] + (double)be1[t];
            sh1[t] = 0.5 * vn * (1.0 + erf(vn * SQRT1_2));
        }
        __syncthreads();

        {
            const int c = t & 127, sl2 = t >> 7;
            const float* w2c = w2 + c;
            const int kb = sl2 * 32;
            double p = 0;
            for (int k = 0; k < 32; ++k)
                p = fma(sh1[kb + k], (double)w2c[(size_t)(kb + k) * H2D], p);
            sPart[sl2 * 128 + c] = p;
        }
        __syncthreads();
        double c2 = 0.0;
        if (t < 128) {
            double p0 = (sPart[0 * 128 + t] + sPart[1 * 128 + t]) + (sPart[2 * 128 + t] + sPart[3 * 128 + t]);
            double p1 = (sPart[4 * 128 + t] + sPart[5 * 128 + t]) + (sPart[6 * 128 + t] + sPart[7 * 128 + t]);
            c2 = (p0 + p1) + (double)b2[t];
            double s1 = c2, s2 = c2 * c2;
            for (int m = 1; m < 64; m <<= 1) { s1 += __shfl_xor(s1, m, 64); s2 += __shfl_xor(s2, m, 64); }
            if (lane == 0) { sred[w * 2] = s1; sred[w * 2 + 1] = s2; }
        }
        __syncthreads();
        if (t < 128) {
            double s1 = sred[0] + sred[2];
            double s2 = sred[1] + sred[3];
            double mu  = s1 * (1.0 / H2D);
            double var = s2 * (1.0 / H2D) - mu * mu;
            double rs  = 1.0 / sqrt(var + 1e-5);
            double vn  = (c2 - mu) * rs * (double)g2[t] + (double)be2[t];
            sh2[t] = 0.5 * vn * (1.0 + erf(vn * SQRT1_2));
        }
        __syncthreads();

        {
            const int c = t & 63, sl3 = t >> 6;
            const float* w3c = w3 + c;
            const int kb = sl3 * 8;
            double p = 0;
            for (int k = 0; k < 8; ++k)
                p = fma(sh2[kb + k], (double)w3c[(size_t)(kb + k) * NE], p);
            sPart[sl3 * 64 + c] = p;
        }
        __syncthreads();
        if (t < NE) {
            double q0 = (sPart[0*64+t]  + sPart[1*64+t])  + (sPart[2*64+t]  + sPart[3*64+t]);
            double q1 = (sPart[4*64+t]  + sPart[5*64+t])  + (sPart[6*64+t]  + sPart[7*64+t]);
            double q2 = (sPart[8*64+t]  + sPart[9*64+t])  + (sPart[10*64+t] + sPart[11*64+t]);
            double q3 = (sPart[12*64+t] + sPart[13*64+t]) + (sPart[14*64+t] + sPart[15*64+t]);
            double lgv = (((q0 + q1) + (q2 + q3)) + (double)b3[t]) * tinv;

            double v1 = lgv, v2 = -INFINITY;
            int i1 = t, i2 = IBIG;
            for (int m = 1; m < 64; m <<= 1) {
                double ov1 = __shfl_xor(v1, m, 64); int oi1 = __shfl_xor(i1, m, 64);
                double ov2 = __shfl_xor(v2, m, 64); int oi2 = __shfl_xor(i2, m, 64);
                bool aw = (v1 > ov1) || (v1 == ov1 && i1 < oi1);
                double wv = aw ? v1  : ov1;  int wi_ = aw ? i1  : oi1;
                double lv = aw ? ov1 : v1;   int li  = aw ? oi1 : i1;
                double sv = aw ? v2  : ov2;  int si  = aw ? i2  : oi2;
                bool sw = (sv > lv) || (sv == lv && si < li);
                v1 = wv; i1 = wi_;
                v2 = sw ? sv : lv;
                i2 = sw ? si : li;
            }
            double e2d = exp(v2 - v1);
            double den = 1.0 + e2d;
            double tg1 = 1.0 / den;
            double tg2 = e2d / den;
            double ssum = tg1 + tg2 + 1e-8;
            float gv1 = (float)(tg1 / ssum);
            float gv2 = (float)(tg2 / ssum);
            if (t == 0) {
                out_idx[(size_t)row * 2 + 0] = (float)i1;
                out_idx[(size_t)row * 2 + 1] = (float)i2;
            }
            out_gates[(size_t)row * NE + t] = (t == i1) ? gv1 : ((t == i2) ? gv2 : 0.0f);
        }
        __syncthreads();
    }
}

extern "C" void kernel_launch(void* const* d_in, const int* in_sizes, int n_in,
                              void* d_out, int out_size, void* d_ws, size_t ws_size,
                              hipStream_t stream)
{
    const float* x    = (const float*)d_in[0];
    const float* w1   = (const float*)d_in[1];
    const float* b1   = (const float*)d_in[2];
    const float* g1   = (const float*)d_in[3];
    const float* be1  = (const float*)d_in[4];
    const float* w2   = (const float*)d_in[5];
    const float* b2   = (const float*)d_in[6];
    const float* g2   = (const float*)d_in[7];
    const float* be2  = (const float*)d_in[8];
    const float* w3   = (const float*)d_in[9];
    const float* b3   = (const float*)d_in[10];
    const float* temp = (const float*)d_in[11];

    float* gates  = (float*)d_out;
    float* idxf   = gates + (size_t)NROWS * NE;
    float* logits = idxf + (size_t)NROWS * 2;

    unsigned int* ws_count = (unsigned int*)d_ws;
    int* ws_rows = (int*)((char*)d_ws + WS_OFF_ROWS);
    unsigned short* w1f_hi = (unsigned short*)((char*)d_ws + WS_OFF_W1FH);
    unsigned short* w1f_lo = (unsigned short*)((char*)d_ws + WS_OFF_W1FL);

    hipLaunchKernelGGL(prep_w1f_kernel, dim3(256), dim3(256), 0, stream, w1, w1f_hi, w1f_lo, ws_count);

    if (ws_size >= WS_NEED_SPLIT) {
        float* h1g = (float*)((char*)d_ws + WS_OFF_H1G);
        hipLaunchKernelGGL(gemm1_ln_kernel, dim3(NROWS / BM), dim3(512), 0, stream,
                           x, b1, g1, be1, w1f_hi, w1f_lo, h1g);
        hipLaunchKernelGGL(tail_kernel, dim3(NROWS / 32), dim3(256), 0, stream,
                           h1g, w2, b2, g2, be2, w3, b3, temp,
                           gates, idxf, logits, ws_count, ws_rows);
    } else {
        hipLaunchKernelGGL(gate_fused_kernel, dim3(NROWS / BM), dim3(512), 0, stream,
                           x, b1, g1, be1, w2, b2, g2, be2, w3, b3, temp,
                           w1f_hi, w1f_lo, gates, idxf, logits, ws_count, ws_rows);
    }
    hipLaunchKernelGGL(repair_f64_kernel, dim3(512), dim3(1024), 0, stream,
                       x, w1, b1, g1, be1, w2, b2, g2, be2, w3, b3, temp,
                       gates, idxf, ws_count, ws_rows);
}

// Round 15
// 196.754 us; speedup vs baseline: 1.5598x; 1.5598x over previous
//
#include <hip/hip_runtime.h>
#include <math.h>

#define NROWS 16384
#define DIN   2048
#define H1D   256
#define H2D   128
#define NE    64
#define EPS_MARGIN 2e-4f
#define SQRT1_2 0.70710678118654752440084436210485
#define IBIG 0x7fffffff

typedef short  bf16x8 __attribute__((ext_vector_type(8)));
typedef float  f32x4  __attribute__((ext_vector_type(4)));
typedef __attribute__((address_space(3))) void lds_void;
typedef __attribute__((address_space(1))) const void glob_void;

#define GLDS16(src, dst) \
    __builtin_amdgcn_global_load_lds((glob_void*)(src), (lds_void*)(dst), 16, 0, 0)

// ---------------- workspace layout ----------------
#define WS_OFF_ROWS 64
#define WS_OFF_W1FH 66560
#define WS_OFF_W1FL (WS_OFF_W1FH + DIN*H1D*2)          // 2163712
#define WS_OFF_H1G  (WS_OFF_W1FL + DIN*H1D*2)          // 4260864
#define WS_NEED_FUSED (size_t)WS_OFF_H1G
#define WS_NEED_SPLIT (size_t)(WS_OFF_H1G + (size_t)NROWS*H1D*4)   // ~20.1 MB

__device__ __forceinline__ void split_bf16(float v, unsigned short& h, unsigned short& l) {
    unsigned int u = __float_as_uint(v);
    unsigned int rh = u + 0x7FFFu + ((u >> 16) & 1u);
    h = (unsigned short)(rh >> 16);
    float hf = __uint_as_float((unsigned int)h << 16);
    float r = v - hf;
    unsigned int u2 = __float_as_uint(r);
    unsigned int rl = u2 + 0x7FFFu + ((u2 >> 16) & 1u);
    l = (unsigned short)(rl >> 16);
}

__device__ __forceinline__ void split_fast(float v, short& h, short& l) {
    unsigned int u = __float_as_uint(v);
    unsigned int rh = (u + 0x7FFFu + ((u >> 16) & 1u)) >> 16;
    h = (short)rh;
    float r = v - __uint_as_float(rh << 16);
    l = (short)(__float_as_uint(r) >> 16);
}

__device__ __forceinline__ bool gtr(float a, int ia, float b, int ib) {
    return a > b || (a == b && ia < ib);
}
__device__ __forceinline__ void ins3(float v, int iv,
                                     float& t1, int& j1, float& t2, int& j2, float& t3, int& j3) {
    if (gtr(v, iv, t1, j1))      { t3 = t2; j3 = j2; t2 = t1; j2 = j1; t1 = v; j1 = iv; }
    else if (gtr(v, iv, t2, j2)) { t3 = t2; j3 = j2; t2 = v;  j2 = iv; }
    else if (gtr(v, iv, t3, j3)) { t3 = v;  j3 = iv; }
}

// ---------------- prep: w1 -> fragment-ordered split-bf16 (+ ws_count init) ----------------
__global__ void prep_w1f_kernel(const float* __restrict__ w1,
                                unsigned short* __restrict__ w1f_hi,
                                unsigned short* __restrict__ w1f_lo,
                                unsigned int* __restrict__ ws_count)
{
    if (blockIdx.x == 0 && threadIdx.x == 0) *ws_count = 0u;
    const int g    = blockIdx.x * 256 + threadIdx.x;
    const int st   = g >> 10;
    const int cb   = (g >> 6) & 15;
    const int lane = g & 63;
    const int col  = cb * 16 + (lane & 15);
    const int k0   = st * 32 + (lane >> 4) * 8;
    unsigned short vh[8], vl[8];
    #pragma unroll
    for (int j = 0; j < 8; ++j) {
        float v = w1[(size_t)(k0 + j) * H1D + col];
        split_bf16(v, vh[j], vl[j]);
    }
    *(uint4*)(w1f_hi + (size_t)g * 8) = *(uint4*)vh;
    *(uint4*)(w1f_lo + (size_t)g * 8) = *(uint4*)vl;
}

// ---------------- GEMM tile geometry (R13, proven) ----------------
#define BM 32
#define KSTEPS (DIN / 32)     // 64
#define OFF_AB  0
#define OFF_BH  8192
#define OFF_BL  40960
#define OFF_H1  0
#define H1P     264
#define OFF_H2  33792
#define H2P     132
#define OFF_RED 50688
#define SMEM_SZ 73728

// ===================== split pass 1: GEMM1 + LN + GELU -> h1g =====================
__global__ __launch_bounds__(512, 4)
void gemm1_ln_kernel(const float* __restrict__ x,
                     const float* __restrict__ b1, const float* __restrict__ g1,
                     const float* __restrict__ be1,
                     const unsigned short* __restrict__ w1f_hi,
                     const unsigned short* __restrict__ w1f_lo,
                     float* __restrict__ h1g)
{
    __shared__ __align__(16) char smem[SMEM_SZ];
    float*  sH1  = (float*)(smem + OFF_H1);
    float2* sRed = (float2*)(smem + OFF_RED);

    const int tid  = threadIdx.x;
    const int lane = tid & 63;
    const int wid  = tid >> 6;
    const int wr   = wid >> 2;
    const int wc   = wid & 3;
    const int lr   = lane & 15;
    const int lg   = lane >> 4;
    const int r0   = blockIdx.x * BM;

    const int arow = (wid & 3) * 8 + (lane >> 3);
    const int aseg = lane & 7;
    const float* asrc = x + (size_t)(r0 + arow) * DIN + ((aseg ^ (arow & 7)) << 2);
    const unsigned short* bsh0 = w1f_hi + ((size_t)((wid * 2 + 0) * 64 + lane)) * 8;
    const unsigned short* bsh1 = w1f_hi + ((size_t)((wid * 2 + 1) * 64 + lane)) * 8;
    const unsigned short* bsl0 = w1f_lo + ((size_t)((wid * 2 + 0) * 64 + lane)) * 8;
    const unsigned short* bsl1 = w1f_lo + ((size_t)((wid * 2 + 1) * 64 + lane)) * 8;

#define STAGE(buf_, st_) do { \
    if (wid < 4) GLDS16(asrc + (size_t)(st_) * 32, smem + OFF_AB + (buf_) * 4096 + wid * 1024); \
    GLDS16(bsh0 + (size_t)(st_) * 8192, smem + OFF_BH + (buf_) * 16384 + (wid * 2 + 0) * 1024); \
    GLDS16(bsh1 + (size_t)(st_) * 8192, smem + OFF_BH + (buf_) * 16384 + (wid * 2 + 1) * 1024); \
    GLDS16(bsl0 + (size_t)(st_) * 8192, smem + OFF_BL + (buf_) * 16384 + (wid * 2 + 0) * 1024); \
    GLDS16(bsl1 + (size_t)(st_) * 8192, smem + OFF_BL + (buf_) * 16384 + (wid * 2 + 1) * 1024); \
} while (0)

    f32x4 acc[4];
    #pragma unroll
    for (int t = 0; t < 4; ++t) acc[t] = (f32x4){0.f, 0.f, 0.f, 0.f};

    STAGE(0, 0);
    __syncthreads();
    int cur = 0;
    for (int st = 0; st < KSTEPS; ++st) {
        if (st + 1 < KSTEPS) STAGE(cur ^ 1, st + 1);
        bf16x8 ah, al;
        {
            int row = wr * 16 + lr;
            int g0  = (2 * lg) ^ (lr & 7);
            const char* abase = smem + OFF_AB + cur * 4096 + row * 128;
            float4 q0 = *(const float4*)(abase + g0 * 16);
            float4 q1 = *(const float4*)(abase + (g0 ^ 1) * 16);
            float af[8] = {q0.x, q0.y, q0.z, q0.w, q1.x, q1.y, q1.z, q1.w};
            #pragma unroll
            for (int j = 0; j < 8; ++j) {
                short h, l;
                split_fast(af[j], h, l);
                ah[j] = h; al[j] = l;
            }
        }
        bf16x8 bh[4], bl[4];
        #pragma unroll
        for (int t = 0; t < 4; ++t) {
            int cb = wc * 4 + t;
            bh[t] = *(const bf16x8*)(smem + OFF_BH + cur * 16384 + cb * 1024 + lane * 16);
            bl[t] = *(const bf16x8*)(smem + OFF_BL + cur * 16384 + cb * 1024 + lane * 16);
        }
        #pragma unroll
        for (int t = 0; t < 4; ++t) {
            acc[t] = __builtin_amdgcn_mfma_f32_16x16x32_bf16(ah, bh[t], acc[t], 0, 0, 0);
            acc[t] = __builtin_amdgcn_mfma_f32_16x16x32_bf16(ah, bl[t], acc[t], 0, 0, 0);
            acc[t] = __builtin_amdgcn_mfma_f32_16x16x32_bf16(al, bh[t], acc[t], 0, 0, 0);
        }
        __syncthreads();
        cur ^= 1;
    }
#undef STAGE

    float tb[4], tg[4], tbe[4];
    #pragma unroll
    for (int t = 0; t < 4; ++t) {
        int col = wc * 64 + t * 16 + lr;
        tb[t] = b1[col]; tg[t] = g1[col]; tbe[t] = be1[col];
    }
    #pragma unroll
    for (int t = 0; t < 4; ++t)
        #pragma unroll
        for (int rg = 0; rg < 4; ++rg)
            acc[t][rg] += tb[t];

    #pragma unroll
    for (int rg = 0; rg < 4; ++rg) {
        float p1 = 0.f, p2 = 0.f;
        #pragma unroll
        for (int t = 0; t < 4; ++t) { float v = acc[t][rg]; p1 += v; p2 += v * v; }
        p1 += __shfl_xor(p1, 1, 64); p2 += __shfl_xor(p2, 1, 64);
        p1 += __shfl_xor(p1, 2, 64); p2 += __shfl_xor(p2, 2, 64);
        p1 += __shfl_xor(p1, 4, 64); p2 += __shfl_xor(p2, 4, 64);
        p1 += __shfl_xor(p1, 8, 64); p2 += __shfl_xor(p2, 8, 64);
        if (lr == 0) {
            int row = wr * 16 + lg * 4 + rg;
            sRed[row * 4 + wc] = make_float2(p1, p2);
        }
    }
    __syncthreads();

    #pragma unroll
    for (int rg = 0; rg < 4; ++rg) {
        int row = wr * 16 + lg * 4 + rg;
        float2 q0 = sRed[row * 4 + 0], q1 = sRed[row * 4 + 1];
        float2 q2 = sRed[row * 4 + 2], q3 = sRed[row * 4 + 3];
        float s1 = (q0.x + q1.x) + (q2.x + q3.x);
        float s2 = (q0.y + q1.y) + (q2.y + q3.y);
        float mu  = s1 * (1.0f / H1D);
        float var = s2 * (1.0f / H1D) - mu * mu;
        float rs  = rsqrtf(var + 1e-5f);
        #pragma unroll
        for (int t = 0; t < 4; ++t) {
            int col = wc * 64 + t * 16 + lr;
            float v = (acc[t][rg] - mu) * rs * tg[t] + tbe[t];
            v = 0.5f * v * (1.0f + erff(v * (float)SQRT1_2));
            sH1[row * H1P + col] = v;
        }
    }
    __syncthreads();

    #pragma unroll
    for (int i = 0; i < 4; ++i) {
        int u = tid + i * 512;
        int row = u >> 6, f4 = u & 63;
        float4 v = *(const float4*)&sH1[row * H1P + f4 * 4];
        *(float4*)(h1g + (size_t)(r0 + row) * H1D + f4 * 4) = v;
    }
}

// ===================== split pass 2: stage2 + stage3 + top-3 =====================
__global__ __launch_bounds__(256, 4)
void tail_kernel(const float* __restrict__ h1g,
                 const float* __restrict__ w2, const float* __restrict__ b2,
                 const float* __restrict__ g2, const float* __restrict__ be2,
                 const float* __restrict__ w3, const float* __restrict__ b3,
                 const float* __restrict__ temperature,
                 float* __restrict__ out_gates,
                 float* __restrict__ out_idx,
                 float* __restrict__ out_logits,
                 unsigned int* __restrict__ ws_count,
                 int* __restrict__ ws_rows)
{
    __shared__ __align__(16) float sH1[32 * H1P];
    __shared__ __align__(16) float sH2[32 * H2P];

    const int tid = threadIdx.x;
    const int r0  = blockIdx.x * 32;

    #pragma unroll
    for (int i = 0; i < 8; ++i) {
        int u = tid + i * 256;
        int row = u >> 6, f4 = u & 63;
        *(float4*)&sH1[row * H1P + f4 * 4] =
            *(const float4*)(h1g + (size_t)(r0 + row) * H1D + f4 * 4);
    }
    __syncthreads();

    const int tx = tid & 31;
    const int ty = tid >> 5;
    float acc2[4][4];
    #pragma unroll
    for (int i = 0; i < 4; ++i)
        #pragma unroll
        for (int j = 0; j < 4; ++j) acc2[i][j] = 0.f;
    {
        const float* w2p = w2 + tx * 4;
        #pragma unroll 2
        for (int k = 0; k < H1D; ++k) {
            float4 wv4 = *(const float4*)(w2p + (size_t)k * H2D);
            float wr4[4] = {wv4.x, wv4.y, wv4.z, wv4.w};
            float ar4[4];
            #pragma unroll
            for (int i = 0; i < 4; ++i) ar4[i] = sH1[(ty * 4 + i) * H1P + k];
            #pragma unroll
            for (int i = 0; i < 4; ++i)
                #pragma unroll
                for (int j = 0; j < 4; ++j)
                    acc2[i][j] = fmaf(ar4[i], wr4[j], acc2[i][j]);
        }
    }
    {
        float b2v[4], g2v[4], be2v[4];
        #pragma unroll
        for (int j = 0; j < 4; ++j) {
            b2v[j] = b2[tx * 4 + j]; g2v[j] = g2[tx * 4 + j]; be2v[j] = be2[tx * 4 + j];
        }
        #pragma unroll
        for (int i = 0; i < 4; ++i) {
            float s1 = 0.f, s2 = 0.f, vv[4];
            #pragma unroll
            for (int j = 0; j < 4; ++j) {
                float v = acc2[i][j] + b2v[j];
                vv[j] = v; s1 += v; s2 += v * v;
            }
            s1 += __shfl_xor(s1, 1, 64);  s2 += __shfl_xor(s2, 1, 64);
            s1 += __shfl_xor(s1, 2, 64);  s2 += __shfl_xor(s2, 2, 64);
            s1 += __shfl_xor(s1, 4, 64);  s2 += __shfl_xor(s2, 4, 64);
            s1 += __shfl_xor(s1, 8, 64);  s2 += __shfl_xor(s2, 8, 64);
            s1 += __shfl_xor(s1, 16, 64); s2 += __shfl_xor(s2, 16, 64);
            float mu  = s1 * (1.0f / H2D);
            float var = s2 * (1.0f / H2D) - mu * mu;
            float rs  = rsqrtf(var + 1e-5f);
            #pragma unroll
            for (int j = 0; j < 4; ++j) {
                float v = (vv[j] - mu) * rs * g2v[j] + be2v[j];
                v = 0.5f * v * (1.0f + erff(v * (float)SQRT1_2));
                sH2[(ty * 4 + i) * H2P + tx * 4 + j] = v;
            }
        }
    }
    __syncthreads();

    const int q = tid & 7;
    const int r = tid >> 3;
    float acc3[8];
    #pragma unroll
    for (int j = 0; j < 8; ++j) acc3[j] = 0.f;
    {
        const float* w3p = w3 + q * 8;
        #pragma unroll 4
        for (int k = 0; k < H2D; ++k) {
            float hv = sH2[r * H2P + k];
            float4 wa = *(const float4*)(w3p + (size_t)k * NE);
            float4 wb = *(const float4*)(w3p + (size_t)k * NE + 4);
            acc3[0] = fmaf(hv, wa.x, acc3[0]);
            acc3[1] = fmaf(hv, wa.y, acc3[1]);
            acc3[2] = fmaf(hv, wa.z, acc3[2]);
            acc3[3] = fmaf(hv, wa.w, acc3[3]);
            acc3[4] = fmaf(hv, wb.x, acc3[4]);
            acc3[5] = fmaf(hv, wb.y, acc3[5]);
            acc3[6] = fmaf(hv, wb.z, acc3[6]);
            acc3[7] = fmaf(hv, wb.w, acc3[7]);
        }
    }
    float tinv = 1.0f / fmaxf(temperature[0], 0.1f);
    float lg8[8];
    #pragma unroll
    for (int j = 0; j < 8; ++j) lg8[j] = (acc3[j] + b3[q * 8 + j]) * tinv;

    *(float4*)(out_logits + (size_t)(r0 + r) * NE + q * 8)     = make_float4(lg8[0], lg8[1], lg8[2], lg8[3]);
    *(float4*)(out_logits + (size_t)(r0 + r) * NE + q * 8 + 4) = make_float4(lg8[4], lg8[5], lg8[6], lg8[7]);

    float v1 = -INFINITY, v2 = -INFINITY, v3 = -INFINITY;
    int   i1 = IBIG, i2 = IBIG, i3 = IBIG;
    #pragma unroll
    for (int j = 0; j < 8; ++j) ins3(lg8[j], q * 8 + j, v1, i1, v2, i2, v3, i3);
    #pragma unroll
    for (int m = 1; m < 8; m <<= 1) {
        float c1v = __shfl_xor(v1, m, 64); int cj1 = __shfl_xor(i1, m, 64);
        float c2v = __shfl_xor(v2, m, 64); int cj2 = __shfl_xor(i2, m, 64);
        float c3v = __shfl_xor(v3, m, 64); int cj3 = __shfl_xor(i3, m, 64);
        ins3(c1v, cj1, v1, i1, v2, i2, v3, i3);
        ins3(c2v, cj2, v1, i1, v2, i2, v3, i3);
        ins3(c3v, cj3, v1, i1, v2, i2, v3, i3);
    }

    float e2  = expf(v2 - v1);
    float den = 1.0f + e2;
    float tg1 = 1.0f / den;
    float tg2 = e2 / den;
    float ssum = tg1 + tg2 + 1e-8f;
    float gv1 = tg1 / ssum;
    float gv2 = tg2 / ssum;

    if (q == 0) {
        float margin = fminf(v1 - v2, v2 - v3);
        if (!(margin >= EPS_MARGIN)) {
            unsigned int slot = atomicAdd(ws_count, 1u);
            if ((int)slot < NROWS) ws_rows[slot] = r0 + r;
        }
        out_idx[(size_t)(r0 + r) * 2 + 0] = (float)i1;
        out_idx[(size_t)(r0 + r) * 2 + 1] = (float)i2;
    }
    {
        float gvv[8];
        #pragma unroll
        for (int j = 0; j < 8; ++j) {
            int c = q * 8 + j;
            gvv[j] = (c == i1) ? gv1 : ((c == i2) ? gv2 : 0.0f);
        }
        *(float4*)(out_gates + (size_t)(r0 + r) * NE + q * 8)     = make_float4(gvv[0], gvv[1], gvv[2], gvv[3]);
        *(float4*)(out_gates + (size_t)(r0 + r) * NE + q * 8 + 4) = make_float4(gvv[4], gvv[5], gvv[6], gvv[7]);
    }
}

// ===================== fused fallback (R13 verbatim, passing) =====================
__global__ __launch_bounds__(512, 4)
void gate_fused_kernel(const float* __restrict__ x,
                       const float* __restrict__ b1, const float* __restrict__ g1,
                       const float* __restrict__ be1,
                       const float* __restrict__ w2, const float* __restrict__ b2,
                       const float* __restrict__ g2, const float* __restrict__ be2,
                       const float* __restrict__ w3, const float* __restrict__ b3,
                       const float* __restrict__ temperature,
                       const unsigned short* __restrict__ w1f_hi,
                       const unsigned short* __restrict__ w1f_lo,
                       float* __restrict__ out_gates,
                       float* __restrict__ out_idx,
                       float* __restrict__ out_logits,
                       unsigned int* __restrict__ ws_count,
                       int* __restrict__ ws_rows)
{
    __shared__ __align__(16) char smem[SMEM_SZ];
    float*  sH1  = (float*)(smem + OFF_H1);
    float*  sH2  = (float*)(smem + OFF_H2);
    float2* sRed = (float2*)(smem + OFF_RED);

    const int tid  = threadIdx.x;
    const int lane = tid & 63;
    const int wid  = tid >> 6;
    const int wr   = wid >> 2;
    const int wc   = wid & 3;
    const int lr   = lane & 15;
    const int lg   = lane >> 4;
    const int r0   = blockIdx.x * BM;

    const int arow = (wid & 3) * 8 + (lane >> 3);
    const int aseg = lane & 7;
    const float* asrc = x + (size_t)(r0 + arow) * DIN + ((aseg ^ (arow & 7)) << 2);
    const unsigned short* bsh0 = w1f_hi + ((size_t)((wid * 2 + 0) * 64 + lane)) * 8;
    const unsigned short* bsh1 = w1f_hi + ((size_t)((wid * 2 + 1) * 64 + lane)) * 8;
    const unsigned short* bsl0 = w1f_lo + ((size_t)((wid * 2 + 0) * 64 + lane)) * 8;
    const unsigned short* bsl1 = w1f_lo + ((size_t)((wid * 2 + 1) * 64 + lane)) * 8;

#define STAGE(buf_, st_) do { \
    if (wid < 4) GLDS16(asrc + (size_t)(st_) * 32, smem + OFF_AB + (buf_) * 4096 + wid * 1024); \
    GLDS16(bsh0 + (size_t)(st_) * 8192, smem + OFF_BH + (buf_) * 16384 + (wid * 2 + 0) * 1024); \
    GLDS16(bsh1 + (size_t)(st_) * 8192, smem + OFF_BH + (buf_) * 16384 + (wid * 2 + 1) * 1024); \
    GLDS16(bsl0 + (size_t)(st_) * 8192, smem + OFF_BL + (buf_) * 16384 + (wid * 2 + 0) * 1024); \
    GLDS16(bsl1 + (size_t)(st_) * 8192, smem + OFF_BL + (buf_) * 16384 + (wid * 2 + 1) * 1024); \
} while (0)

    f32x4 acc[4];
    #pragma unroll
    for (int t = 0; t < 4; ++t) acc[t] = (f32x4){0.f, 0.f, 0.f, 0.f};

    STAGE(0, 0);
    __syncthreads();
    int cur = 0;
    for (int st = 0; st < KSTEPS; ++st) {
        if (st + 1 < KSTEPS) STAGE(cur ^ 1, st + 1);
        bf16x8 ah, al;
        {
            int row = wr * 16 + lr;
            int g0  = (2 * lg) ^ (lr & 7);
            const char* abase = smem + OFF_AB + cur * 4096 + row * 128;
            float4 q0 = *(const float4*)(abase + g0 * 16);
            float4 q1 = *(const float4*)(abase + (g0 ^ 1) * 16);
            float af[8] = {q0.x, q0.y, q0.z, q0.w, q1.x, q1.y, q1.z, q1.w};
            #pragma unroll
            for (int j = 0; j < 8; ++j) {
                short h, l;
                split_fast(af[j], h, l);
                ah[j] = h; al[j] = l;
            }
        }
        bf16x8 bh[4], bl[4];
        #pragma unroll
        for (int t = 0; t < 4; ++t) {
            int cb = wc * 4 + t;
            bh[t] = *(const bf16x8*)(smem + OFF_BH + cur * 16384 + cb * 1024 + lane * 16);
            bl[t] = *(const bf16x8*)(smem + OFF_BL + cur * 16384 + cb * 1024 + lane * 16);
        }
        #pragma unroll
        for (int t = 0; t < 4; ++t) {
            acc[t] = __builtin_amdgcn_mfma_f32_16x16x32_bf16(ah, bh[t], acc[t], 0, 0, 0);
            acc[t] = __builtin_amdgcn_mfma_f32_16x16x32_bf16(ah, bl[t], acc[t], 0, 0, 0);
            acc[t] = __builtin_amdgcn_mfma_f32_16x16x32_bf16(al, bh[t], acc[t], 0, 0, 0);
        }
        __syncthreads();
        cur ^= 1;
    }
#undef STAGE

    float tb[4], tg[4], tbe[4];
    #pragma unroll
    for (int t = 0; t < 4; ++t) {
        int col = wc * 64 + t * 16 + lr;
        tb[t] = b1[col]; tg[t] = g1[col]; tbe[t] = be1[col];
    }
    #pragma unroll
    for (int t = 0; t < 4; ++t)
        #pragma unroll
        for (int rg = 0; rg < 4; ++rg)
            acc[t][rg] += tb[t];

    #pragma unroll
    for (int rg = 0; rg < 4; ++rg) {
        float p1 = 0.f, p2 = 0.f;
        #pragma unroll
        for (int t = 0; t < 4; ++t) { float v = acc[t][rg]; p1 += v; p2 += v * v; }
        p1 += __shfl_xor(p1, 1, 64); p2 += __shfl_xor(p2, 1, 64);
        p1 += __shfl_xor(p1, 2, 64); p2 += __shfl_xor(p2, 2, 64);
        p1 += __shfl_xor(p1, 4, 64); p2 += __shfl_xor(p2, 4, 64);
        p1 += __shfl_xor(p1, 8, 64); p2 += __shfl_xor(p2, 8, 64);
        if (lr == 0) {
            int row = wr * 16 + lg * 4 + rg;
            sRed[row * 4 + wc] = make_float2(p1, p2);
        }
    }
    __syncthreads();

    #pragma unroll
    for (int rg = 0; rg < 4; ++rg) {
        int row = wr * 16 + lg * 4 + rg;
        float2 q0 = sRed[row * 4 + 0], q1 = sRed[row * 4 + 1];
        float2 q2 = sRed[row * 4 + 2], q3 = sRed[row * 4 + 3];
        float s1 = (q0.x + q1.x) + (q2.x + q3.x);
        float s2 = (q0.y + q1.y) + (q2.y + q3.y);
        float mu  = s1 * (1.0f / H1D);
        float var = s2 * (1.0f / H1D) - mu * mu;
        float rs  = rsqrtf(var + 1e-5f);
        #pragma unroll
        for (int t = 0; t < 4; ++t) {
            int col = wc * 64 + t * 16 + lr;
            float v = (acc[t][rg] - mu) * rs * tg[t] + tbe[t];
            v = 0.5f * v * (1.0f + erff(v * (float)SQRT1_2));
            sH1[row * H1P + col] = v;
        }
    }
    __syncthreads();

    const int tx = tid & 31;
    const int ty = tid >> 5;
    float acc2[2][4];
    #pragma unroll
    for (int i = 0; i < 2; ++i)
        #pragma unroll
        for (int j = 0; j < 4; ++j) acc2[i][j] = 0.f;
    {
        const float* w2p = w2 + tx * 4;
        #pragma unroll 4
        for (int k = 0; k < H1D; ++k) {
            float4 wv4 = *(const float4*)(w2p + (size_t)k * H2D);
            float wr4[4] = {wv4.x, wv4.y, wv4.z, wv4.w};
            float ar0 = sH1[(ty * 2 + 0) * H1P + k];
            float ar1 = sH1[(ty * 2 + 1) * H1P + k];
            #pragma unroll
            for (int j = 0; j < 4; ++j) {
                acc2[0][j] = fmaf(ar0, wr4[j], acc2[0][j]);
                acc2[1][j] = fmaf(ar1, wr4[j], acc2[1][j]);
            }
        }
    }
    {
        float b2v[4], g2v[4], be2v[4];
        #pragma unroll
        for (int j = 0; j < 4; ++j) {
            b2v[j] = b2[tx * 4 + j]; g2v[j] = g2[tx * 4 + j]; be2v[j] = be2[tx * 4 + j];
        }
        #pragma unroll
        for (int i = 0; i < 2; ++i) {
            float s1 = 0.f, s2 = 0.f, vv[4];
            #pragma unroll
            for (int j = 0; j < 4; ++j) {
                float v = acc2[i][j] + b2v[j];
                vv[j] = v; s1 += v; s2 += v * v;
            }
            s1 += __shfl_xor(s1, 1, 64);  s2 += __shfl_xor(s2, 1, 64);
            s1 += __shfl_xor(s1, 2, 64);  s2 += __shfl_xor(s2, 2, 64);
            s1 += __shfl_xor(s1, 4, 64);  s2 += __shfl_xor(s2, 4, 64);
            s1 += __shfl_xor(s1, 8, 64);  s2 += __shfl_xor(s2, 8, 64);
            s1 += __shfl_xor(s1, 16, 64); s2 += __shfl_xor(s2, 16, 64);
            float mu  = s1 * (1.0f / H2D);
            float var = s2 * (1.0f / H2D) - mu * mu;
            float rs  = rsqrtf(var + 1e-5f);
            #pragma unroll
            for (int j = 0; j < 4; ++j) {
                float v = (vv[j] - mu) * rs * g2v[j] + be2v[j];
                v = 0.5f * v * (1.0f + erff(v * (float)SQRT1_2));
                sH2[(ty * 2 + i) * H2P + tx * 4 + j] = v;
            }
        }
    }
    __syncthreads();

    const int q = tid & 15;
    const int r = tid >> 4;
    float acc3[4];
    #pragma unroll
    for (int j = 0; j < 4; ++j) acc3[j] = 0.f;
    {
        const float* w3p = w3 + q * 4;
        #pragma unroll 4
        for (int k = 0; k < H2D; ++k) {
            float hv = sH2[r * H2P + k];
            float4 wa = *(const float4*)(w3p + (size_t)k * NE);
            acc3[0] = fmaf(hv, wa.x, acc3[0]);
            acc3[1] = fmaf(hv, wa.y, acc3[1]);
            acc3[2] = fmaf(hv, wa.z, acc3[2]);
            acc3[3] = fmaf(hv, wa.w, acc3[3]);
        }
    }
    float tinv = 1.0f / fmaxf(temperature[0], 0.1f);
    float lg4[4];
    #pragma unroll
    for (int j = 0; j < 4; ++j) lg4[j] = (acc3[j] + b3[q * 4 + j]) * tinv;

    *(float4*)(out_logits + (size_t)(r0 + r) * NE + q * 4) = make_float4(lg4[0], lg4[1], lg4[2], lg4[3]);

    float v1 = -INFINITY, v2 = -INFINITY, v3 = -INFINITY;
    int   i1 = IBIG, i2 = IBIG, i3 = IBIG;
    #pragma unroll
    for (int j = 0; j < 4; ++j) ins3(lg4[j], q * 4 + j, v1, i1, v2, i2, v3, i3);
    #pragma unroll
    for (int m = 1; m < 16; m <<= 1) {
        float c1v = __shfl_xor(v1, m, 64); int cj1 = __shfl_xor(i1, m, 64);
        float c2v = __shfl_xor(v2, m, 64); int cj2 = __shfl_xor(i2, m, 64);
        float c3v = __shfl_xor(v3, m, 64); int cj3 = __shfl_xor(i3, m, 64);
        ins3(c1v, cj1, v1, i1, v2, i2, v3, i3);
        ins3(c2v, cj2, v1, i1, v2, i2, v3, i3);
        ins3(c3v, cj3, v1, i1, v2, i2, v3, i3);
    }

    float e2  = expf(v2 - v1);
    float den = 1.0f + e2;
    float tg1 = 1.0f / den;
    float tg2 = e2 / den;
    float ssum = tg1 + tg2 + 1e-8f;
    float gv1 = tg1 / ssum;
    float gv2 = tg2 / ssum;

    if (q == 0) {
        float margin = fminf(v1 - v2, v2 - v3);
        if (!(margin >= EPS_MARGIN)) {
            unsigned int slot = atomicAdd(ws_count, 1u);
            if ((int)slot < NROWS) ws_rows[slot] = r0 + r;
        }
        out_idx[(size_t)(r0 + r) * 2 + 0] = (float)i1;
        out_idx[(size_t)(r0 + r) * 2 + 1] = (float)i2;
    }
    {
        float gvv[4];
        #pragma unroll
        for (int j = 0; j < 4; ++j) {
            int c = q * 4 + j;
            gvv[j] = (c == i1) ? gv1 : ((c == i2) ? gv2 : 0.0f);
        }
        *(float4*)(out_gates + (size_t)(r0 + r) * NE + q * 4) = make_float4(gvv[0], gvv[1], gvv[2], gvv[3]);
    }
}

// ---------------- pass B: f64 repair — load-batched (same math, same order) ----------------
__global__ __launch_bounds__(1024, 1)
void repair_f64_kernel(const float* __restrict__ x,
                       const float* __restrict__ w1, const float* __restrict__ b1,
                       const float* __restrict__ g1, const float* __restrict__ be1,
                       const float* __restrict__ w2, const float* __restrict__ b2,
                       const float* __restrict__ g2, const float* __restrict__ be2,
                       const float* __restrict__ w3, const float* __restrict__ b3,
                       const float* __restrict__ temperature,
                       float* __restrict__ out_gates,
                       float* __restrict__ out_idx,
                       const unsigned int* __restrict__ ws_count,
                       const int* __restrict__ ws_rows)
{
    __shared__ float  sxr[DIN];
    __shared__ double sPart[1024];
    __shared__ double sh1[H1D];
    __shared__ double sh2[H2D];
    __shared__ double sred[32];

    const int t = threadIdx.x;
    const int lane = t & 63, w = t >> 6;
    const unsigned int n = *ws_count;
    const double tinv = 1.0 / fmax((double)temperature[0], 0.1);

    for (unsigned int wi = blockIdx.x; wi < n; wi += gridDim.x) {
        const int row = ws_rows[wi];

        const float4* xr4 = (const float4*)(x + (size_t)row * DIN);
        if (t < DIN / 4) ((float4*)sxr)[t] = xr4[t];
        __syncthreads();

        // ---- stage 1: batch 16 w1 loads per round (chain order preserved) ----
        {
            const int c = t & 255, sl = t >> 8;
            const float* w1c = w1 + c;
            const int kb = sl * 512;
            double a0 = 0, a1 = 0, a2 = 0, a3 = 0;
            for (int k = 0; k < 512; k += 16) {
                float wv[16];
                #pragma unroll
                for (int j = 0; j < 16; ++j)
                    wv[j] = w1c[(size_t)(kb + k + j) * H1D];
                float xv[16];
                #pragma unroll
                for (int j = 0; j < 16; ++j) xv[j] = sxr[kb + k + j];
                #pragma unroll
                for (int j = 0; j < 16; j += 4) {
                    a0 = fma((double)xv[j + 0], (double)wv[j + 0], a0);
                    a1 = fma((double)xv[j + 1], (double)wv[j + 1], a1);
                    a2 = fma((double)xv[j + 2], (double)wv[j + 2], a2);
                    a3 = fma((double)xv[j + 3], (double)wv[j + 3], a3);
                }
            }
            sPart[sl * 256 + c] = (a0 + a1) + (a2 + a3);
        }
        __syncthreads();
        double c1 = 0.0;
        if (t < 256) {
            c1 = ((sPart[0 * 256 + t] + sPart[1 * 256 + t]) +
                  (sPart[2 * 256 + t] + sPart[3 * 256 + t])) + (double)b1[t];
            double s1 = c1, s2 = c1 * c1;
            for (int m = 1; m < 64; m <<= 1) { s1 += __shfl_xor(s1, m, 64); s2 += __shfl_xor(s2, m, 64); }
            if (lane == 0) { sred[w * 2] = s1; sred[w * 2 + 1] = s2; }
        }
        __syncthreads();
        if (t < 256) {
            double s1 = (sred[0] + sred[2]) + (sred[4] + sred[6]);
            double s2 = (sred[1] + sred[3]) + (sred[5] + sred[7]);
            double mu  = s1 * (1.0 / H1D);
            double var = s2 * (1.0 / H1D) - mu * mu;
            double rs  = 1.0 / sqrt(var + 1e-5);
            double vn  = (c1 - mu) * rs * (double)g1[t] + (double)be1[t];
            sh1[t] = 0.5 * vn * (1.0 + erf(vn * SQRT1_2));
        }
        __syncthreads();

        // ---- stage 2: batch all 32 w2 loads (single-chain order preserved) ----
        {
            const int c = t & 127, sl2 = t >> 7;
            const float* w2c = w2 + c;
            const int kb = sl2 * 32;
            float w2v[32];
            #pragma unroll
            for (int j = 0; j < 32; ++j)
                w2v[j] = w2c[(size_t)(kb + j) * H2D];
            double p = 0;
            #pragma unroll
            for (int j = 0; j < 32; ++j)
                p = fma(sh1[kb + j], (double)w2v[j], p);
            sPart[sl2 * 128 + c] = p;
        }
        __syncthreads();
        double c2 = 0.0;
        if (t < 128) {
            double p0 = (sPart[0 * 128 + t] + sPart[1 * 128 + t]) + (sPart[2 * 128 + t] + sPart[3 * 128 + t]);
            double p1 = (sPart[4 * 128 + t] + sPart[5 * 128 + t]) + (sPart[6 * 128 + t] + sPart[7 * 128 + t]);
            c2 = (p0 + p1) + (double)b2[t];
            double s1 = c2, s2 = c2 * c2;
            for (int m = 1; m < 64; m <<= 1) { s1 += __shfl_xor(s1, m, 64); s2 += __shfl_xor(s2, m, 64); }
            if (lane == 0) { sred[w * 2] = s1; sred[w * 2 + 1] = s2; }
        }
        __syncthreads();
        if (t < 128) {
            double s1 = sred[0] + sred[2];
            double s2 = sred[1] + sred[3];
            double mu  = s1 * (1.0 / H2D);
            double var = s2 * (1.0 / H2D) - mu * mu;
            double rs  = 1.0 / sqrt(var + 1e-5);
            double vn  = (c2 - mu) * rs * (double)g2[t] + (double)be2[t];
            sh2[t] = 0.5 * vn * (1.0 + erf(vn * SQRT1_2));
        }
        __syncthreads();

        // ---- stage 3: batch all 8 w3 loads (single-chain order preserved) ----
        {
            const int c = t & 63, sl3 = t >> 6;
            const float* w3c = w3 + c;
            const int kb = sl3 * 8;
            float w3v[8];
            #pragma unroll
            for (int j = 0; j < 8; ++j)
                w3v[j] = w3c[(size_t)(kb + j) * NE];
            double p = 0;
            #pragma unroll
            for (int j = 0; j < 8; ++j)
                p = fma(sh2[kb + j], (double)w3v[j], p);
            sPart[sl3 * 64 + c] = p;
        }
        __syncthreads();
        if (t < NE) {
            double q0 = (sPart[0*64+t]  + sPart[1*64+t])  + (sPart[2*64+t]  + sPart[3*64+t]);
            double q1 = (sPart[4*64+t]  + sPart[5*64+t])  + (sPart[6*64+t]  + sPart[7*64+t]);
            double q2 = (sPart[8*64+t]  + sPart[9*64+t])  + (sPart[10*64+t] + sPart[11*64+t]);
            double q3 = (sPart[12*64+t] + sPart[13*64+t]) + (sPart[14*64+t] + sPart[15*64+t]);
            double lgv = (((q0 + q1) + (q2 + q3)) + (double)b3[t]) * tinv;

            double v1 = lgv, v2 = -INFINITY;
            int i1 = t, i2 = IBIG;
            for (int m = 1; m < 64; m <<= 1) {
                double ov1 = __shfl_xor(v1, m, 64); int oi1 = __shfl_xor(i1, m, 64);
                double ov2 = __shfl_xor(v2, m, 64); int oi2 = __shfl_xor(i2, m, 64);
                bool aw = (v1 > ov1) || (v1 == ov1 && i1 < oi1);
                double wv = aw ? v1  : ov1;  int wi_ = aw ? i1  : oi1;
                double lv = aw ? ov1 : v1;   int li  = aw ? oi1 : i1;
                double sv = aw ? v2  : ov2;  int si  = aw ? i2  : oi2;
                bool sw = (sv > lv) || (sv == lv && si < li);
                v1 = wv; i1 = wi_;
                v2 = sw ? sv : lv;
                i2 = sw ? si : li;
            }
            double e2d = exp(v2 - v1);
            double den = 1.0 + e2d;
            double tg1 = 1.0 / den;
            double tg2 = e2d / den;
            double ssum = tg1 + tg2 + 1e-8;
            float gv1 = (float)(tg1 / ssum);
            float gv2 = (float)(tg2 / ssum);
            if (t == 0) {
                out_idx[(size_t)row * 2 + 0] = (float)i1;
                out_idx[(size_t)row * 2 + 1] = (float)i2;
            }
            out_gates[(size_t)row * NE + t] = (t == i1) ? gv1 : ((t == i2) ? gv2 : 0.0f);
        }
        __syncthreads();
    }
}

extern "C" void kernel_launch(void* const* d_in, const int* in_sizes, int n_in,
                              void* d_out, int out_size, void* d_ws, size_t ws_size,
                              hipStream_t stream)
{
    const float* x    = (const float*)d_in[0];
    const float* w1   = (const float*)d_in[1];
    const float* b1   = (const float*)d_in[2];
    const float* g1   = (const float*)d_in[3];
    const float* be1  = (const float*)d_in[4];
    const float* w2   = (const float*)d_in[5];
    const float* b2   = (const float*)d_in[6];
    const float* g2   = (const float*)d_in[7];
    const float* be2  = (const float*)d_in[8];
    const float* w3   = (const float*)d_in[9];
    const float* b3   = (const float*)d_in[10];
    const float* temp = (const float*)d_in[11];

    float* gates  = (float*)d_out;
    float* idxf   = gates + (size_t)NROWS * NE;
    float* logits = idxf + (size_t)NROWS * 2;

    unsigned int* ws_count = (unsigned int*)d_ws;
    int* ws_rows = (int*)((char*)d_ws + WS_OFF_ROWS);
    unsigned short* w1f_hi = (unsigned short*)((char*)d_ws + WS_OFF_W1FH);
    unsigned short* w1f_lo = (unsigned short*)((char*)d_ws + WS_OFF_W1FL);

    hipLaunchKernelGGL(prep_w1f_kernel, dim3(256), dim3(256), 0, stream, w1, w1f_hi, w1f_lo, ws_count);

    if (ws_size >= WS_NEED_SPLIT) {
        float* h1g = (float*)((char*)d_ws + WS_OFF_H1G);
        hipLaunchKernelGGL(gemm1_ln_kernel, dim3(NROWS / BM), dim3(512), 0, stream,
                           x, b1, g1, be1, w1f_hi, w1f_lo, h1g);
        hipLaunchKernelGGL(tail_kernel, dim3(NROWS / 32), dim3(256), 0, stream,
                           h1g, w2, b2, g2, be2, w3, b3, temp,
                           gates, idxf, logits, ws_count, ws_rows);
    } else {
        hipLaunchKernelGGL(gate_fused_kernel, dim3(NROWS / BM), dim3(512), 0, stream,
                           x, b1, g1, be1, w2, b2, g2, be2, w3, b3, temp,
                           w1f_hi, w1f_lo, gates, idxf, logits, ws_count, ws_rows);
    }
    hipLaunchKernelGGL(repair_f64_kernel, dim3(512), dim3(1024), 0, stream,
                       x, w1, b1, g1, be1, w2, b2, g2, be2, w3, b3, temp,
                       gates, idxf, ws_count, ws_rows);
}